// Round 1
// baseline (344.705 us; speedup 1.0000x reference)
//
#include <hip/hip_runtime.h>
#include <hip/hip_bf16.h>

typedef __bf16 bf16x8 __attribute__((ext_vector_type(8)));
typedef float f32x4 __attribute__((ext_vector_type(4)));

#define NTOK 16384
#define DIN  256
#define DHID 512
#define DOUT 256
#define NEXP 8

#define MFMA16(a, b, c) __builtin_amdgcn_mfma_f32_16x16x32_bf16(a, b, c, 0, 0, 0)

// ---------------------------------------------------------------------------
// x (f32) -> xbf (bf16), coalesced. 8 elems/thread.
__global__ __launch_bounds__(256) void xcvt_kernel(const float* __restrict__ x,
                                                   __bf16* __restrict__ xbf) {
  int t = blockIdx.x * 256 + threadIdx.x;
  const float4* s = (const float4*)x + (size_t)t * 2;
  float4 v0 = s[0], v1 = s[1];
  bf16x8 o;
  o[0] = (__bf16)v0.x; o[1] = (__bf16)v0.y; o[2] = (__bf16)v0.z; o[3] = (__bf16)v0.w;
  o[4] = (__bf16)v1.x; o[5] = (__bf16)v1.y; o[6] = (__bf16)v1.z; o[7] = (__bf16)v1.w;
  *(bf16x8*)(xbf + (size_t)t * 8) = o;
}

// ---------------------------------------------------------------------------
// src [E][K][N] f32 -> dst [E][N][K] bf16 (transpose), N = 1<<nsh (pow2).
// Coalesced reads (consecutive lanes -> consecutive n); 16B writes.
__global__ __launch_bounds__(256) void wcvt_kernel(const float* __restrict__ src,
                                                   __bf16* __restrict__ dst,
                                                   int K, int nsh) {
  int e = blockIdx.y;
  int flat = blockIdx.x * 256 + threadIdx.x;  // [0, N*K/8)
  int N = 1 << nsh;
  int kg = flat >> nsh;
  int n = flat & (N - 1);
  const float* s = src + ((size_t)e * K + (size_t)kg * 8) * N + n;
  bf16x8 t;
#pragma unroll
  for (int j = 0; j < 8; ++j) t[j] = (__bf16)s[(size_t)j * N];
  *(bf16x8*)(dst + (size_t)((e << nsh) + n) * K + kg * 8) = t;
}

// ---------------------------------------------------------------------------
// Gating: one thread per token. fp32 chunk dots + fp64 combine (selection must
// match numpy's fp32 logits to ~1e-6 so top-2 doesn't flip on near-ties).
// Ties: first index wins (matches lax.top_k stable descending sort).
__global__ __launch_bounds__(64) void gate_kernel(const float* __restrict__ x,
                                                  const float* __restrict__ wg,
                                                  int* __restrict__ cnt,
                                                  int* __restrict__ btok,
                                                  float* __restrict__ bw) {
  __shared__ __align__(16) float wgl[DIN * NEXP];  // [k][e], 8 KB; reads are
  const int tid = threadIdx.x;                     // wave-uniform -> broadcast
  const float4* wg4 = (const float4*)wg;
  float4* wgl4 = (float4*)wgl;
#pragma unroll
  for (int i = 0; i < 8; ++i) wgl4[tid + 64 * i] = wg4[tid + 64 * i];
  __syncthreads();

  const int token = blockIdx.x * 64 + tid;
  const f32x4* xr = (const f32x4*)(x + (size_t)token * DIN);
  double acc[NEXP];
#pragma unroll
  for (int e = 0; e < NEXP; ++e) acc[e] = 0.0;

  for (int c8 = 0; c8 < 8; ++c8) {
    f32x4 p0 = {0.f, 0.f, 0.f, 0.f}, p1 = {0.f, 0.f, 0.f, 0.f};
#pragma unroll
    for (int j4 = 0; j4 < 8; ++j4) {
      f32x4 xv = xr[c8 * 8 + j4];
      const float* wr = wgl + (c8 * 32 + j4 * 4) * 8;
#pragma unroll
      for (int d = 0; d < 4; ++d) {
        float xs_ = xv[d];
        f32x4 wlo = *(const f32x4*)(wr + 8 * d);
        f32x4 whi = *(const f32x4*)(wr + 8 * d + 4);
        p0 += xs_ * wlo;
        p1 += xs_ * whi;
      }
    }
#pragma unroll
    for (int d = 0; d < 4; ++d) {
      acc[d] += (double)p0[d];
      acc[4 + d] += (double)p1[d];
    }
  }

  double bv1 = acc[0];
  int i1 = 0;
#pragma unroll
  for (int e = 1; e < NEXP; ++e)
    if (acc[e] > bv1) { bv1 = acc[e]; i1 = e; }
  double bv2 = -1e300;
  int i2 = 0;
#pragma unroll
  for (int e = 0; e < NEXP; ++e)
    if (e != i1 && acc[e] > bv2) { bv2 = acc[e]; i2 = e; }

  // softmax over the two selected logits (top1 is the max)
  float dd = expf((float)(bv2 - bv1));
  float w1 = 1.0f / (1.0f + dd);
  float w2 = dd * w1;

  int p1s = atomicAdd(&cnt[i1], 1);
  btok[i1 * NTOK + p1s] = token;
  bw[i1 * NTOK + p1s] = w1;
  int p2s = atomicAdd(&cnt[i2], 1);
  btok[i2 * NTOK + p2s] = token;
  bw[i2 * NTOK + p2s] = w2;
}

// ---------------------------------------------------------------------------
// Expert FFN: grid (tile, expert); 64 gathered tokens per block; 4 waves.
// Per h-chunk (64 cols): S = x@W1c (+b1, relu) -> h (LDS) ; acc += h@W2c.
// MFMA 16x16x32 bf16. A-frags from XOR-swizzled LDS (conflict-free b128),
// B-frags 16B gathers from transposed bf16 weights (L2-resident).
// Epilogue: atomicAdd(out[token], w*(acc+b2)). Pad rows get weight 0.
__global__ __launch_bounds__(256, 2) void ffn_kernel(
    const __bf16* __restrict__ xbf, const __bf16* __restrict__ w1bf,
    const __bf16* __restrict__ w2bf, const float* __restrict__ b1g,
    const float* __restrict__ b2g, const int* __restrict__ cnt,
    const int* __restrict__ btok, const float* __restrict__ bw,
    float* __restrict__ out) {
  __shared__ __align__(16) __bf16 xs[64 * 256];  // swizzled [m][k]
  __shared__ __align__(16) __bf16 hs[64 * 64];   // swizzled [m][k]
  __shared__ int tok[64];
  __shared__ float wgt[64];
  __shared__ float b2s[DOUT];

  const int tid = threadIdx.x;
  const int e = blockIdx.y;
  const int ce = cnt[e];
  const int start = blockIdx.x * 64;
  if (start >= ce) return;

  if (tid < 64) {
    int idx = start + tid;
    bool v = idx < ce;
    tok[tid] = v ? btok[e * NTOK + idx] : 0;
    wgt[tid] = v ? bw[e * NTOK + idx] : 0.0f;
  }
  b2s[tid] = b2g[e * DOUT + tid];
  __syncthreads();

  // gather x rows (bf16) into swizzled LDS: chunk c' = c ^ (row&7)
#pragma unroll
  for (int i = 0; i < 8; ++i) {
    int flat = tid + 256 * i;
    int row = flat >> 5, cc = flat & 31;
    const uint4* src = (const uint4*)(xbf + (size_t)tok[row] * DIN) + cc;
    int cs = cc ^ (row & 7);
    *(uint4*)((char*)xs + row * 512 + cs * 16) = *src;
  }
  __syncthreads();

  const int lane = tid & 63;
  const int wid = tid >> 6;
  const int l15 = lane & 15;
  const int quad = lane >> 4;
  const int wm = wid >> 1;  // 0..1 : m-half
  const int wn = wid & 1;   // 0..1 : n-half

  f32x4 acc[2][8];
#pragma unroll
  for (int mi = 0; mi < 2; ++mi)
#pragma unroll
    for (int ni = 0; ni < 8; ++ni) acc[mi][ni] = (f32x4){0.f, 0.f, 0.f, 0.f};

  for (int c = 0; c < 8; ++c) {
    // ---- phase A: S[32m x 32n] = x @ W1[:, c*64+wn*32 .. +32]
    f32x4 S[2][2];
#pragma unroll
    for (int mi = 0; mi < 2; ++mi)
#pragma unroll
      for (int ni = 0; ni < 2; ++ni) S[mi][ni] = (f32x4){0.f, 0.f, 0.f, 0.f};

    const __bf16* w1b = w1bf + (size_t)(e * DHID + c * 64 + wn * 32) * DIN + quad * 8;
#pragma unroll
    for (int kc = 0; kc < 8; ++kc) {
      int m0 = wm * 32 + l15;
      int m1 = m0 + 16;
      bf16x8 a0 = *(const bf16x8*)((char*)xs + m0 * 512 +
                                   ((((kc << 2) | quad) ^ (m0 & 7)) << 4));
      bf16x8 a1 = *(const bf16x8*)((char*)xs + m1 * 512 +
                                   ((((kc << 2) | quad) ^ (m1 & 7)) << 4));
      bf16x8 bb0 = *(const bf16x8*)(w1b + (size_t)l15 * DIN + kc * 32);
      bf16x8 bb1 = *(const bf16x8*)(w1b + (size_t)(l15 + 16) * DIN + kc * 32);
      S[0][0] = MFMA16(a0, bb0, S[0][0]);
      S[0][1] = MFMA16(a0, bb1, S[0][1]);
      S[1][0] = MFMA16(a1, bb0, S[1][0]);
      S[1][1] = MFMA16(a1, bb1, S[1][1]);
    }
    // bias + relu -> hs (swizzled). C-layout: row = quad*4+r, col = l15.
#pragma unroll
    for (int ni = 0; ni < 2; ++ni) {
      int nloc = wn * 32 + ni * 16 + l15;  // 0..63 within chunk
      float bv = b1g[e * DHID + c * 64 + nloc];
#pragma unroll
      for (int mi = 0; mi < 2; ++mi) {
#pragma unroll
        for (int r = 0; r < 4; ++r) {
          int m = wm * 32 + mi * 16 + quad * 4 + r;
          float v = fmaxf(S[mi][ni][r] + bv, 0.f);
          *((__bf16*)((char*)hs + m * 128 + ((((nloc >> 3) ^ (m & 7)) << 4) |
                                             ((nloc & 7) << 1)))) = (__bf16)v;
        }
      }
    }
    __syncthreads();

    // ---- phase B: acc[32m x 128n] += h @ W2[c*64.., :]
    const __bf16* w2b = w2bf + (size_t)(e * DOUT + wn * 128) * DHID + c * 64 + quad * 8;
#pragma unroll
    for (int kc = 0; kc < 2; ++kc) {
      int m0 = wm * 32 + l15;
      int m1 = m0 + 16;
      bf16x8 h0 = *(const bf16x8*)((char*)hs + m0 * 128 +
                                   ((((kc << 2) | quad) ^ (m0 & 7)) << 4));
      bf16x8 h1 = *(const bf16x8*)((char*)hs + m1 * 128 +
                                   ((((kc << 2) | quad) ^ (m1 & 7)) << 4));
#pragma unroll
      for (int ni = 0; ni < 8; ++ni) {
        bf16x8 bb = *(const bf16x8*)(w2b + (size_t)(ni * 16 + l15) * DHID + kc * 32);
        acc[0][ni] = MFMA16(h0, bb, acc[0][ni]);
        acc[1][ni] = MFMA16(h1, bb, acc[1][ni]);
      }
    }
    __syncthreads();
  }

  // ---- epilogue: out[token] += w * (acc + b2)
#pragma unroll
  for (int mi = 0; mi < 2; ++mi) {
#pragma unroll
    for (int r = 0; r < 4; ++r) {
      int m = wm * 32 + mi * 16 + quad * 4 + r;
      float wv = wgt[m];
      float* orow = out + (size_t)tok[m] * DOUT;
#pragma unroll
      for (int ni = 0; ni < 8; ++ni) {
        int n = wn * 128 + ni * 16 + l15;
        atomicAdd(orow + n, wv * (acc[mi][ni][r] + b2s[n]));
      }
    }
  }
}

// ---------------------------------------------------------------------------
extern "C" void kernel_launch(void* const* d_in, const int* in_sizes, int n_in,
                              void* d_out, int out_size, void* d_ws, size_t ws_size,
                              hipStream_t stream) {
  const float* x = (const float*)d_in[0];
  const float* Wg = (const float*)d_in[1];
  const float* W1 = (const float*)d_in[2];
  const float* b1 = (const float*)d_in[3];
  const float* W2 = (const float*)d_in[4];
  const float* b2 = (const float*)d_in[5];
  float* out = (float*)d_out;

  char* ws = (char*)d_ws;
  int* cnt = (int*)(ws + 0);                    //      32 B
  int* btok = (int*)(ws + 256);                 //  512 KiB
  float* bw = (float*)(ws + 524544);            //  512 KiB
  __bf16* xbf = (__bf16*)(ws + 1048832);        //    8 MiB
  __bf16* w1bf = (__bf16*)(ws + 9437440);       //    2 MiB
  __bf16* w2bf = (__bf16*)(ws + 11534592);      //    2 MiB  (end 13631744)

  hipMemsetAsync(out, 0, (size_t)NTOK * DOUT * sizeof(float), stream);
  hipMemsetAsync(cnt, 0, NEXP * sizeof(int), stream);

  xcvt_kernel<<<dim3(NTOK * DIN / 8 / 256), dim3(256), 0, stream>>>(x, xbf);
  wcvt_kernel<<<dim3(64, NEXP), dim3(256), 0, stream>>>(W1, w1bf, DIN, 9);   // ->[E][512][256]
  wcvt_kernel<<<dim3(64, NEXP), dim3(256), 0, stream>>>(W2, w2bf, DHID, 8);  // ->[E][256][512]
  gate_kernel<<<dim3(NTOK / 64), dim3(64), 0, stream>>>(x, Wg, cnt, btok, bw);
  ffn_kernel<<<dim3(256, NEXP), dim3(256), 0, stream>>>(xbf, w1bf, w2bf, b1, b2,
                                                        cnt, btok, bw, out);
}

// Round 2
// 232.756 us; speedup vs baseline: 1.4810x; 1.4810x over previous
//
#include <hip/hip_runtime.h>
#include <hip/hip_bf16.h>

typedef __bf16 bf16x8 __attribute__((ext_vector_type(8)));
typedef float f32x4 __attribute__((ext_vector_type(4)));

#define NTOK 16384
#define DIN  256
#define DHID 512
#define DOUT 256
#define NEXP 8

#define MFMA16(a, b, c) __builtin_amdgcn_mfma_f32_16x16x32_bf16(a, b, c, 0, 0, 0)

// ---------------------------------------------------------------------------
// x (f32) -> xbf (bf16), coalesced. 8 elems/thread.
__global__ __launch_bounds__(256) void xcvt_kernel(const float* __restrict__ x,
                                                   __bf16* __restrict__ xbf) {
  int t = blockIdx.x * 256 + threadIdx.x;
  const float4* s = (const float4*)x + (size_t)t * 2;
  float4 v0 = s[0], v1 = s[1];
  bf16x8 o;
  o[0] = (__bf16)v0.x; o[1] = (__bf16)v0.y; o[2] = (__bf16)v0.z; o[3] = (__bf16)v0.w;
  o[4] = (__bf16)v1.x; o[5] = (__bf16)v1.y; o[6] = (__bf16)v1.z; o[7] = (__bf16)v1.w;
  *(bf16x8*)(xbf + (size_t)t * 8) = o;
}

// ---------------------------------------------------------------------------
// src [E][K][N] f32 -> dst [E][N][K] bf16 (transpose), N = 1<<nsh (pow2).
__global__ __launch_bounds__(256) void wcvt_kernel(const float* __restrict__ src,
                                                   __bf16* __restrict__ dst,
                                                   int K, int nsh) {
  int e = blockIdx.y;
  int flat = blockIdx.x * 256 + threadIdx.x;  // [0, N*K/8)
  int N = 1 << nsh;
  int kg = flat >> nsh;
  int n = flat & (N - 1);
  const float* s = src + ((size_t)e * K + (size_t)kg * 8) * N + n;
  bf16x8 t;
#pragma unroll
  for (int j = 0; j < 8; ++j) t[j] = (__bf16)s[(size_t)j * N];
  *(bf16x8*)(dst + (size_t)((e << nsh) + n) * K + kg * 8) = t;
}

// ---------------------------------------------------------------------------
// Gating, round-2 layout: 8 lanes per token, 32 tokens per 256-thread block.
// Each lane: fp32 partial dot over a 32-dim slice for all 8 experts (same
// within-chunk fp32 order as the round-1 passing version), f64 shuffle-tree
// combine across the 8 lanes, leader lane (sub==0) does top-2 + softmax.
// Bucket append: LDS-aggregated counts -> 8 global atomics per block.
__global__ __launch_bounds__(256) void gate_kernel(const float* __restrict__ x,
                                                   const float* __restrict__ wg,
                                                   int* __restrict__ cnt,
                                                   int* __restrict__ btok,
                                                   float* __restrict__ bw) {
  __shared__ int lcnt[NEXP];
  __shared__ int lbase[NEXP];
  const int tid = threadIdx.x;
  if (tid < NEXP) lcnt[tid] = 0;

  const int sub = tid & 7;        // 32-dim slice
  const int tslot = tid >> 3;     // 0..31
  const int token = blockIdx.x * 32 + tslot;
  const f32x4* xr = (const f32x4*)(x + (size_t)token * DIN + sub * 32);
  const float* wr0 = wg + (size_t)sub * 32 * NEXP;  // Wg is [256][8], L1-resident

  f32x4 p0 = {0.f, 0.f, 0.f, 0.f}, p1 = {0.f, 0.f, 0.f, 0.f};
#pragma unroll
  for (int j4 = 0; j4 < 8; ++j4) {
    f32x4 xv = xr[j4];
    const float* wr = wr0 + j4 * 32;
#pragma unroll
    for (int d = 0; d < 4; ++d) {
      float xs_ = xv[d];
      p0 += xs_ * *(const f32x4*)(wr + 8 * d);
      p1 += xs_ * *(const f32x4*)(wr + 8 * d + 4);
    }
  }
  double acc[NEXP];
#pragma unroll
  for (int d = 0; d < 4; ++d) {
    acc[d] = (double)p0[d];
    acc[4 + d] = (double)p1[d];
  }
  // combine the 8 lane-slices (f64 tree; ~1e-15 vs sequential order)
#pragma unroll
  for (int off = 1; off < 8; off <<= 1)
#pragma unroll
    for (int e = 0; e < NEXP; ++e) acc[e] += __shfl_xor(acc[e], off, 64);

  __syncthreads();  // lcnt zeroing visible before leader atomics

  int i1 = 0, i2 = 0, o1 = 0, o2 = 0;
  float w1 = 0.f, w2 = 0.f;
  if (sub == 0) {
    double bv1 = acc[0];
#pragma unroll
    for (int e = 1; e < NEXP; ++e)
      if (acc[e] > bv1) { bv1 = acc[e]; i1 = e; }
    double bv2 = -1e300;
#pragma unroll
    for (int e = 0; e < NEXP; ++e)
      if (e != i1 && acc[e] > bv2) { bv2 = acc[e]; i2 = e; }
    float dd = expf((float)(bv2 - bv1));
    w1 = 1.0f / (1.0f + dd);
    w2 = dd * w1;
    o1 = atomicAdd(&lcnt[i1], 1);  // LDS atomics: cheap block aggregation
    o2 = atomicAdd(&lcnt[i2], 1);
  }
  __syncthreads();
  if (tid < NEXP) lbase[tid] = atomicAdd(&cnt[tid], lcnt[tid]);
  __syncthreads();
  if (sub == 0) {
    int s1 = lbase[i1] + o1, s2 = lbase[i2] + o2;
    btok[i1 * NTOK + s1] = token;
    bw[i1 * NTOK + s1] = w1;
    btok[i2 * NTOK + s2] = token;
    bw[i2 * NTOK + s2] = w2;
  }
}

// ---------------------------------------------------------------------------
// Expert FFN: grid (tile, expert); 64 gathered tokens per block; 4 waves.
// Per h-chunk (64 cols): S = x@W1c (+b1, relu) -> h (LDS) ; acc += h@W2c.
// MFMA 16x16x32 bf16. A-frags from XOR-swizzled LDS (conflict-free b128),
// B-frags 16B gathers from transposed bf16 weights (L2-resident).
// Epilogue: atomicAdd(out[token], w*(acc+b2)). Pad rows get weight 0.
__global__ __launch_bounds__(256, 2) void ffn_kernel(
    const __bf16* __restrict__ xbf, const __bf16* __restrict__ w1bf,
    const __bf16* __restrict__ w2bf, const float* __restrict__ b1g,
    const float* __restrict__ b2g, const int* __restrict__ cnt,
    const int* __restrict__ btok, const float* __restrict__ bw,
    float* __restrict__ out) {
  __shared__ __align__(16) __bf16 xs[64 * 256];  // swizzled [m][k]
  __shared__ __align__(16) __bf16 hs[64 * 64];   // swizzled [m][k]
  __shared__ int tok[64];
  __shared__ float wgt[64];
  __shared__ float b2s[DOUT];

  const int tid = threadIdx.x;
  const int e = blockIdx.y;
  const int ce = cnt[e];
  const int start = blockIdx.x * 64;
  if (start >= ce) return;

  if (tid < 64) {
    int idx = start + tid;
    bool v = idx < ce;
    tok[tid] = v ? btok[e * NTOK + idx] : 0;
    wgt[tid] = v ? bw[e * NTOK + idx] : 0.0f;
  }
  b2s[tid] = b2g[e * DOUT + tid];
  __syncthreads();

  // gather x rows (bf16) into swizzled LDS: chunk c' = c ^ (row&7)
#pragma unroll
  for (int i = 0; i < 8; ++i) {
    int flat = tid + 256 * i;
    int row = flat >> 5, cc = flat & 31;
    const uint4* src = (const uint4*)(xbf + (size_t)tok[row] * DIN) + cc;
    int cs = cc ^ (row & 7);
    *(uint4*)((char*)xs + row * 512 + cs * 16) = *src;
  }
  __syncthreads();

  const int lane = tid & 63;
  const int wid = tid >> 6;
  const int l15 = lane & 15;
  const int quad = lane >> 4;
  const int wm = wid >> 1;  // 0..1 : m-half
  const int wn = wid & 1;   // 0..1 : n-half

  f32x4 acc[2][8];
#pragma unroll
  for (int mi = 0; mi < 2; ++mi)
#pragma unroll
    for (int ni = 0; ni < 8; ++ni) acc[mi][ni] = (f32x4){0.f, 0.f, 0.f, 0.f};

  for (int c = 0; c < 8; ++c) {
    // ---- phase A: S[32m x 32n] = x @ W1[:, c*64+wn*32 .. +32]
    f32x4 S[2][2];
#pragma unroll
    for (int mi = 0; mi < 2; ++mi)
#pragma unroll
      for (int ni = 0; ni < 2; ++ni) S[mi][ni] = (f32x4){0.f, 0.f, 0.f, 0.f};

    const __bf16* w1b = w1bf + (size_t)(e * DHID + c * 64 + wn * 32) * DIN + quad * 8;
#pragma unroll
    for (int kc = 0; kc < 8; ++kc) {
      int m0 = wm * 32 + l15;
      int m1 = m0 + 16;
      bf16x8 a0 = *(const bf16x8*)((char*)xs + m0 * 512 +
                                   ((((kc << 2) | quad) ^ (m0 & 7)) << 4));
      bf16x8 a1 = *(const bf16x8*)((char*)xs + m1 * 512 +
                                   ((((kc << 2) | quad) ^ (m1 & 7)) << 4));
      bf16x8 bb0 = *(const bf16x8*)(w1b + (size_t)l15 * DIN + kc * 32);
      bf16x8 bb1 = *(const bf16x8*)(w1b + (size_t)(l15 + 16) * DIN + kc * 32);
      S[0][0] = MFMA16(a0, bb0, S[0][0]);
      S[0][1] = MFMA16(a0, bb1, S[0][1]);
      S[1][0] = MFMA16(a1, bb0, S[1][0]);
      S[1][1] = MFMA16(a1, bb1, S[1][1]);
    }
    // bias + relu -> hs (swizzled). C-layout: row = quad*4+r, col = l15.
#pragma unroll
    for (int ni = 0; ni < 2; ++ni) {
      int nloc = wn * 32 + ni * 16 + l15;  // 0..63 within chunk
      float bv = b1g[e * DHID + c * 64 + nloc];
#pragma unroll
      for (int mi = 0; mi < 2; ++mi) {
#pragma unroll
        for (int r = 0; r < 4; ++r) {
          int m = wm * 32 + mi * 16 + quad * 4 + r;
          float v = fmaxf(S[mi][ni][r] + bv, 0.f);
          *((__bf16*)((char*)hs + m * 128 + ((((nloc >> 3) ^ (m & 7)) << 4) |
                                             ((nloc & 7) << 1)))) = (__bf16)v;
        }
      }
    }
    __syncthreads();

    // ---- phase B: acc[32m x 128n] += h @ W2[c*64.., :]
    const __bf16* w2b = w2bf + (size_t)(e * DOUT + wn * 128) * DHID + c * 64 + quad * 8;
#pragma unroll
    for (int kc = 0; kc < 2; ++kc) {
      int m0 = wm * 32 + l15;
      int m1 = m0 + 16;
      bf16x8 h0 = *(const bf16x8*)((char*)hs + m0 * 128 +
                                   ((((kc << 2) | quad) ^ (m0 & 7)) << 4));
      bf16x8 h1 = *(const bf16x8*)((char*)hs + m1 * 128 +
                                   ((((kc << 2) | quad) ^ (m1 & 7)) << 4));
#pragma unroll
      for (int ni = 0; ni < 8; ++ni) {
        bf16x8 bb = *(const bf16x8*)(w2b + (size_t)(ni * 16 + l15) * DHID + kc * 32);
        acc[0][ni] = MFMA16(h0, bb, acc[0][ni]);
        acc[1][ni] = MFMA16(h1, bb, acc[1][ni]);
      }
    }
    __syncthreads();
  }

  // ---- epilogue: out[token] += w * (acc + b2)
#pragma unroll
  for (int mi = 0; mi < 2; ++mi) {
#pragma unroll
    for (int r = 0; r < 4; ++r) {
      int m = wm * 32 + mi * 16 + quad * 4 + r;
      float wv = wgt[m];
      float* orow = out + (size_t)tok[m] * DOUT;
#pragma unroll
      for (int ni = 0; ni < 8; ++ni) {
        int n = wn * 128 + ni * 16 + l15;
        atomicAdd(orow + n, wv * (acc[mi][ni][r] + b2s[n]));
      }
    }
  }
}

// ---------------------------------------------------------------------------
extern "C" void kernel_launch(void* const* d_in, const int* in_sizes, int n_in,
                              void* d_out, int out_size, void* d_ws, size_t ws_size,
                              hipStream_t stream) {
  const float* x = (const float*)d_in[0];
  const float* Wg = (const float*)d_in[1];
  const float* W1 = (const float*)d_in[2];
  const float* b1 = (const float*)d_in[3];
  const float* W2 = (const float*)d_in[4];
  const float* b2 = (const float*)d_in[5];
  float* out = (float*)d_out;

  char* ws = (char*)d_ws;
  int* cnt = (int*)(ws + 0);                    //      32 B
  int* btok = (int*)(ws + 256);                 //  512 KiB
  float* bw = (float*)(ws + 524544);            //  512 KiB
  __bf16* xbf = (__bf16*)(ws + 1048832);        //    8 MiB
  __bf16* w1bf = (__bf16*)(ws + 9437440);       //    2 MiB
  __bf16* w2bf = (__bf16*)(ws + 11534592);      //    2 MiB  (end 13631744)

  hipMemsetAsync(out, 0, (size_t)NTOK * DOUT * sizeof(float), stream);
  hipMemsetAsync(cnt, 0, NEXP * sizeof(int), stream);

  xcvt_kernel<<<dim3(NTOK * DIN / 8 / 256), dim3(256), 0, stream>>>(x, xbf);
  wcvt_kernel<<<dim3(64, NEXP), dim3(256), 0, stream>>>(W1, w1bf, DIN, 9);   // ->[E][512][256]
  wcvt_kernel<<<dim3(64, NEXP), dim3(256), 0, stream>>>(W2, w2bf, DHID, 8);  // ->[E][256][512]
  gate_kernel<<<dim3(NTOK / 32), dim3(256), 0, stream>>>(x, Wg, cnt, btok, bw);
  ffn_kernel<<<dim3(256, NEXP), dim3(256), 0, stream>>>(xbf, w1bf, w2bf, b1, b2,
                                                        cnt, btok, bw, out);
}

// Round 3
// 184.235 us; speedup vs baseline: 1.8710x; 1.2634x over previous
//
#include <hip/hip_runtime.h>
#include <hip/hip_bf16.h>

typedef __bf16 bf16x8 __attribute__((ext_vector_type(8)));
typedef __bf16 bf16x4 __attribute__((ext_vector_type(4)));
typedef float f32x4 __attribute__((ext_vector_type(4)));

#define NTOK 16384
#define DIN  256
#define DHID 512
#define DOUT 256
#define NEXP 8

#define MFMA16(a, b, c) __builtin_amdgcn_mfma_f32_16x16x32_bf16(a, b, c, 0, 0, 0)
// async global->LDS, 16B/lane; LDS dest = wave-uniform base + lane*16 (HW rule)
#define GLD16(gp, lp)                                                       \
  __builtin_amdgcn_global_load_lds(                                         \
      (__attribute__((address_space(1))) void*)(gp),                        \
      (__attribute__((address_space(3))) void*)(lp), 16, 0, 0)

// ---------------------------------------------------------------------------
// src [E][K][N] f32 -> dst [E][N][K] bf16 (transpose), N = 1<<nsh (pow2).
__global__ __launch_bounds__(256) void wcvt_kernel(const float* __restrict__ src,
                                                   __bf16* __restrict__ dst,
                                                   int K, int nsh) {
  int e = blockIdx.y;
  int flat = blockIdx.x * 256 + threadIdx.x;  // [0, N*K/8)
  int N = 1 << nsh;
  int kg = flat >> nsh;
  int n = flat & (N - 1);
  const float* s = src + ((size_t)e * K + (size_t)kg * 8) * N + n;
  bf16x8 t;
#pragma unroll
  for (int j = 0; j < 8; ++j) t[j] = (__bf16)s[(size_t)j * N];
  *(bf16x8*)(dst + (size_t)((e << nsh) + n) * K + kg * 8) = t;
}

// ---------------------------------------------------------------------------
// Gating (8 lanes/token, 32 tokens/block) + fused x->bf16 conversion.
__global__ __launch_bounds__(256) void gate_kernel(const float* __restrict__ x,
                                                   const float* __restrict__ wg,
                                                   int* __restrict__ cnt,
                                                   int* __restrict__ btok,
                                                   float* __restrict__ bw,
                                                   __bf16* __restrict__ xbf) {
  __shared__ int lcnt[NEXP];
  __shared__ int lbase[NEXP];
  const int tid = threadIdx.x;
  if (tid < NEXP) lcnt[tid] = 0;

  const int sub = tid & 7;        // 32-dim slice
  const int tslot = tid >> 3;     // 0..31
  const int token = blockIdx.x * 32 + tslot;
  const f32x4* xr = (const f32x4*)(x + (size_t)token * DIN + sub * 32);
  const float* wr0 = wg + (size_t)sub * 32 * NEXP;

  bf16x8 xb[4];
  f32x4 p0 = {0.f, 0.f, 0.f, 0.f}, p1 = {0.f, 0.f, 0.f, 0.f};
#pragma unroll
  for (int j4 = 0; j4 < 8; ++j4) {
    f32x4 xv = xr[j4];
    const float* wr = wr0 + j4 * 32;
#pragma unroll
    for (int d = 0; d < 4; ++d) {
      float xs_ = xv[d];
      p0 += xs_ * *(const f32x4*)(wr + 8 * d);
      p1 += xs_ * *(const f32x4*)(wr + 8 * d + 4);
      xb[j4 >> 1][(j4 & 1) * 4 + d] = (__bf16)xs_;
    }
  }
  // fused bf16 store of this lane's 32-elem slice
  {
    bf16x8* xdst = (bf16x8*)(xbf + (size_t)token * DIN + sub * 32);
#pragma unroll
    for (int i = 0; i < 4; ++i) xdst[i] = xb[i];
  }

  double acc[NEXP];
#pragma unroll
  for (int d = 0; d < 4; ++d) {
    acc[d] = (double)p0[d];
    acc[4 + d] = (double)p1[d];
  }
#pragma unroll
  for (int off = 1; off < 8; off <<= 1)
#pragma unroll
    for (int e = 0; e < NEXP; ++e) acc[e] += __shfl_xor(acc[e], off, 64);

  __syncthreads();  // lcnt zeroing visible

  int i1 = 0, i2 = 0, o1 = 0, o2 = 0;
  float w1 = 0.f, w2 = 0.f;
  if (sub == 0) {
    double bv1 = acc[0];
#pragma unroll
    for (int e = 1; e < NEXP; ++e)
      if (acc[e] > bv1) { bv1 = acc[e]; i1 = e; }
    double bv2 = -1e300;
#pragma unroll
    for (int e = 0; e < NEXP; ++e)
      if (e != i1 && acc[e] > bv2) { bv2 = acc[e]; i2 = e; }
    float dd = expf((float)(bv2 - bv1));
    w1 = 1.0f / (1.0f + dd);
    w2 = dd * w1;
    o1 = atomicAdd(&lcnt[i1], 1);
    o2 = atomicAdd(&lcnt[i2], 1);
  }
  __syncthreads();
  if (tid < NEXP) lbase[tid] = atomicAdd(&cnt[tid], lcnt[tid]);
  __syncthreads();
  if (sub == 0) {
    int s1 = lbase[i1] + o1, s2 = lbase[i2] + o2;
    btok[i1 * NTOK + s1] = token;
    bw[i1 * NTOK + s1] = w1;
    btok[i2 * NTOK + s2] = token;
    bw[i2 * NTOK + s2] = w2;
  }
}

// ---------------------------------------------------------------------------
// Expert FFN, round 3: weights staged per-chunk into LDS via global_load_lds
// (swizzle realized by permuting per-lane GLOBAL addresses; LDS side linear),
// x-fragments held in registers, phase-A operands swapped so hs writes are
// 8B ds_write_b64 (conflict-free) and b1 loads are f32x4.
// LDS: wb1 32K + wb2 32K + hs 8K + misc ~1.5K -> 2 blocks/CU.
__global__ __launch_bounds__(256, 2) void ffn_kernel(
    const __bf16* __restrict__ xbf, const __bf16* __restrict__ w1bf,
    const __bf16* __restrict__ w2bf, const float* __restrict__ b1g,
    const float* __restrict__ b2g, const int* __restrict__ cnt,
    const int* __restrict__ btok, const float* __restrict__ bw,
    float* __restrict__ out) {
  __shared__ __align__(16) __bf16 wb1[64 * 256];   // W1 chunk [n64][k256], slot = c ^ (n&31)
  __shared__ __align__(16) __bf16 wb2[256 * 64];   // W2 chunk [n256][k64], slot = c ^ (n&7)
  __shared__ __align__(16) __bf16 hs[64 * 64];     // h [m64][k64], slot = c ^ (m&7)
  __shared__ int tok[64];
  __shared__ float wgt[64];
  __shared__ float b2s[DOUT];

  const int tid = threadIdx.x;
  const int e = blockIdx.y;
  const int ce = cnt[e];
  const int start = blockIdx.x * 64;
  if (start >= ce) return;

  if (tid < 64) {
    int idx = start + tid;
    bool v = idx < ce;
    tok[tid] = v ? btok[e * NTOK + idx] : 0;
    wgt[tid] = v ? bw[e * NTOK + idx] : 0.0f;
  }
  b2s[tid] = b2g[e * DOUT + tid];
  __syncthreads();

  const int lane = tid & 63;
  const int wid = tid >> 6;
  const int l15 = lane & 15;
  const int quad = lane >> 4;
  const int wh = wid >> 1;  // phase A: hid half   / phase B: token half (wm)
  const int wt = wid & 1;   // phase A: token half / phase B: out half  (wn)

  // x fragments in registers: tokens wt*32 + {l15, l15+16}, full K=256.
  bf16x8 xA[2][8];
  {
    const __bf16* r0 = xbf + (size_t)tok[wt * 32 + l15] * DIN + quad * 8;
    const __bf16* r1 = xbf + (size_t)tok[wt * 32 + 16 + l15] * DIN + quad * 8;
#pragma unroll
    for (int kc = 0; kc < 8; ++kc) {
      xA[0][kc] = *(const bf16x8*)(r0 + kc * 32);
      xA[1][kc] = *(const bf16x8*)(r1 + kc * 32);
    }
  }

  f32x4 acc[2][8];
#pragma unroll
  for (int mi = 0; mi < 2; ++mi)
#pragma unroll
    for (int ni = 0; ni < 8; ++ni) acc[mi][ni] = (f32x4){0.f, 0.f, 0.f, 0.f};

  const __bf16* w1e = w1bf + (size_t)e * DHID * DIN;
  const __bf16* w2e = w2bf + (size_t)e * DOUT * DHID;
  const int r1n = lane >> 5, s1 = lane & 31;  // W1 staging: row-in-window, slot
  const int r2n = lane >> 3, s2 = lane & 7;   // W2 staging

  for (int hc = 0; hc < 8; ++hc) {
    __syncthreads();  // previous chunk's readers of wb1/wb2/hs done

    // stage W1c (32 KiB) + W2c (32 KiB); swizzle via global-address permute
#pragma unroll
    for (int j = 0; j < 8; ++j) {
      int W = wid * 8 + j;                 // 1KB window: rows 2W, 2W+1
      int n = 2 * W + r1n;
      int c = s1 ^ (n & 31);
      GLD16(w1e + (size_t)(hc * 64 + n) * DIN + c * 8, wb1 + W * 512);
    }
#pragma unroll
    for (int j = 0; j < 8; ++j) {
      int W = wid * 8 + j;                 // 1KB window: rows 8W..8W+7
      int n = 8 * W + r2n;
      int c = s2 ^ (n & 7);
      GLD16(w2e + (size_t)n * DHID + hc * 64 + c * 8, wb2 + W * 512);
    }
    __syncthreads();  // staging visible

    // ---- phase A: S[hid 32][tok 32] = W1c-half x x-half  (A=W1, B=x)
    f32x4 S[2][2];
#pragma unroll
    for (int nh = 0; nh < 2; ++nh)
#pragma unroll
      for (int mt = 0; mt < 2; ++mt) S[nh][mt] = (f32x4){0.f, 0.f, 0.f, 0.f};
#pragma unroll
    for (int kc = 0; kc < 8; ++kc) {
      int sl = ((kc << 2) | quad) ^ l15;
      bf16x8 w0 = *(const bf16x8*)((const char*)wb1 + (wh * 32 + l15) * 512 + sl * 16);
      bf16x8 w1v = *(const bf16x8*)((const char*)wb1 + (wh * 32 + 16 + l15) * 512 + (sl ^ 16) * 16);
      S[0][0] = MFMA16(w0, xA[0][kc], S[0][0]);
      S[0][1] = MFMA16(w0, xA[1][kc], S[0][1]);
      S[1][0] = MFMA16(w1v, xA[0][kc], S[1][0]);
      S[1][1] = MFMA16(w1v, xA[1][kc], S[1][1]);
    }
    // bias + relu -> hs; lane owns 4 consecutive hid -> one 8B write per tile
#pragma unroll
    for (int nh = 0; nh < 2; ++nh) {
      int kl = wh * 32 + nh * 16 + quad * 4;  // local hid, 4-aligned
      f32x4 bv = *(const f32x4*)(b1g + e * DHID + hc * 64 + kl);
      int cpart = kl >> 3;
      int boff = (kl & 7) << 1;
#pragma unroll
      for (int mt = 0; mt < 2; ++mt) {
        int m = wt * 32 + mt * 16 + l15;
        bf16x4 pk;
#pragma unroll
        for (int r = 0; r < 4; ++r)
          pk[r] = (__bf16)fmaxf(S[nh][mt][r] + bv[r], 0.f);
        *(bf16x4*)((char*)hs + m * 128 + ((cpart ^ (m & 7)) << 4) + boff) = pk;
      }
    }
    __syncthreads();  // hs visible

    // ---- phase B: acc[tok 32][out 128] += h x W2c   (A=h, B=W2)
#pragma unroll
    for (int kc = 0; kc < 2; ++kc) {
      int c = (kc << 2) | quad;
      int m0 = wh * 32 + l15, m1 = m0 + 16;
      bf16x8 h0 = *(const bf16x8*)((const char*)hs + m0 * 128 + ((c ^ (m0 & 7)) << 4));
      bf16x8 h1 = *(const bf16x8*)((const char*)hs + m1 * 128 + ((c ^ (m1 & 7)) << 4));
#pragma unroll
      for (int ni = 0; ni < 8; ++ni) {
        int n = wt * 128 + ni * 16 + l15;
        bf16x8 bb = *(const bf16x8*)((const char*)wb2 + n * 128 + ((c ^ (n & 7)) << 4));
        acc[0][ni] = MFMA16(h0, bb, acc[0][ni]);
        acc[1][ni] = MFMA16(h1, bb, acc[1][ni]);
      }
    }
  }

  // ---- epilogue: out[token] += w * (acc + b2)
#pragma unroll
  for (int mi = 0; mi < 2; ++mi) {
#pragma unroll
    for (int r = 0; r < 4; ++r) {
      int m = wh * 32 + mi * 16 + quad * 4 + r;
      float wv = wgt[m];
      float* orow = out + (size_t)tok[m] * DOUT;
#pragma unroll
      for (int ni = 0; ni < 8; ++ni) {
        int n = wt * 128 + ni * 16 + l15;
        atomicAdd(orow + n, wv * (acc[mi][ni][r] + b2s[n]));
      }
    }
  }
}

// ---------------------------------------------------------------------------
extern "C" void kernel_launch(void* const* d_in, const int* in_sizes, int n_in,
                              void* d_out, int out_size, void* d_ws, size_t ws_size,
                              hipStream_t stream) {
  const float* x = (const float*)d_in[0];
  const float* Wg = (const float*)d_in[1];
  const float* W1 = (const float*)d_in[2];
  const float* b1 = (const float*)d_in[3];
  const float* W2 = (const float*)d_in[4];
  const float* b2 = (const float*)d_in[5];
  float* out = (float*)d_out;

  char* ws = (char*)d_ws;
  int* cnt = (int*)(ws + 0);                    //      32 B
  int* btok = (int*)(ws + 256);                 //  512 KiB
  float* bw = (float*)(ws + 524544);            //  512 KiB
  __bf16* xbf = (__bf16*)(ws + 1048832);        //    8 MiB
  __bf16* w1bf = (__bf16*)(ws + 9437440);       //    2 MiB
  __bf16* w2bf = (__bf16*)(ws + 11534592);      //    2 MiB  (end 13631744)

  hipMemsetAsync(out, 0, (size_t)NTOK * DOUT * sizeof(float), stream);
  hipMemsetAsync(cnt, 0, NEXP * sizeof(int), stream);

  wcvt_kernel<<<dim3(64, NEXP), dim3(256), 0, stream>>>(W1, w1bf, DIN, 9);   // ->[E][512][256]
  wcvt_kernel<<<dim3(64, NEXP), dim3(256), 0, stream>>>(W2, w2bf, DHID, 8);  // ->[E][256][512]
  gate_kernel<<<dim3(NTOK / 32), dim3(256), 0, stream>>>(x, Wg, cnt, btok, bw, xbf);
  ffn_kernel<<<dim3(256, NEXP), dim3(256), 0, stream>>>(xbf, w1bf, w2bf, b1, b2,
                                                        cnt, btok, bw, out);
}

// Round 4
// 170.998 us; speedup vs baseline: 2.0158x; 1.0774x over previous
//
#include <hip/hip_runtime.h>
#include <hip/hip_bf16.h>

typedef __bf16 bf16x8 __attribute__((ext_vector_type(8)));
typedef __bf16 bf16x4 __attribute__((ext_vector_type(4)));
typedef float f32x4 __attribute__((ext_vector_type(4)));

#define NTOK 16384
#define DIN  256
#define DHID 512
#define DOUT 256
#define NEXP 8

#define MFMA16(a, b, c) __builtin_amdgcn_mfma_f32_16x16x32_bf16(a, b, c, 0, 0, 0)
// async global->LDS, 16B/lane; LDS dest = wave-uniform base + lane*16 (HW rule)
#define GLD16(gp, lp)                                                       \
  __builtin_amdgcn_global_load_lds(                                         \
      (__attribute__((address_space(1))) void*)(gp),                        \
      (__attribute__((address_space(3))) void*)(lp), 16, 0, 0)

// ---------------------------------------------------------------------------
// src [E][K][N] f32 -> dst [E][N][K] bf16 (transpose), N = 1<<nsh (pow2).
__global__ __launch_bounds__(256) void wcvt_kernel(const float* __restrict__ src,
                                                   __bf16* __restrict__ dst,
                                                   int K, int nsh) {
  int e = blockIdx.y;
  int flat = blockIdx.x * 256 + threadIdx.x;  // [0, N*K/8)
  int N = 1 << nsh;
  int kg = flat >> nsh;
  int n = flat & (N - 1);
  const float* s = src + ((size_t)e * K + (size_t)kg * 8) * N + n;
  bf16x8 t;
#pragma unroll
  for (int j = 0; j < 8; ++j) t[j] = (__bf16)s[(size_t)j * N];
  *(bf16x8*)(dst + (size_t)((e << nsh) + n) * K + kg * 8) = t;
}

// ---------------------------------------------------------------------------
// Gating (8 lanes/token, 32 tokens/block) + fused x->bf16 conversion.
// Bucket entry packs the pick slot (0 = top1, 1 = top2) in bit 14.
__global__ __launch_bounds__(256) void gate_kernel(const float* __restrict__ x,
                                                   const float* __restrict__ wg,
                                                   int* __restrict__ cnt,
                                                   int* __restrict__ btok,
                                                   float* __restrict__ bw,
                                                   __bf16* __restrict__ xbf) {
  __shared__ int lcnt[NEXP];
  __shared__ int lbase[NEXP];
  const int tid = threadIdx.x;
  if (tid < NEXP) lcnt[tid] = 0;

  const int sub = tid & 7;        // 32-dim slice
  const int tslot = tid >> 3;     // 0..31
  const int token = blockIdx.x * 32 + tslot;
  const f32x4* xr = (const f32x4*)(x + (size_t)token * DIN + sub * 32);
  const float* wr0 = wg + (size_t)sub * 32 * NEXP;

  bf16x8 xb[4];
  f32x4 p0 = {0.f, 0.f, 0.f, 0.f}, p1 = {0.f, 0.f, 0.f, 0.f};
#pragma unroll
  for (int j4 = 0; j4 < 8; ++j4) {
    f32x4 xv = xr[j4];
    const float* wr = wr0 + j4 * 32;
#pragma unroll
    for (int d = 0; d < 4; ++d) {
      float xs_ = xv[d];
      p0 += xs_ * *(const f32x4*)(wr + 8 * d);
      p1 += xs_ * *(const f32x4*)(wr + 8 * d + 4);
      xb[j4 >> 1][(j4 & 1) * 4 + d] = (__bf16)xs_;
    }
  }
  {
    bf16x8* xdst = (bf16x8*)(xbf + (size_t)token * DIN + sub * 32);
#pragma unroll
    for (int i = 0; i < 4; ++i) xdst[i] = xb[i];
  }

  double acc[NEXP];
#pragma unroll
  for (int d = 0; d < 4; ++d) {
    acc[d] = (double)p0[d];
    acc[4 + d] = (double)p1[d];
  }
#pragma unroll
  for (int off = 1; off < 8; off <<= 1)
#pragma unroll
    for (int e = 0; e < NEXP; ++e) acc[e] += __shfl_xor(acc[e], off, 64);

  __syncthreads();  // lcnt zeroing visible

  int i1 = 0, i2 = 0, o1 = 0, o2 = 0;
  float w1 = 0.f, w2 = 0.f;
  if (sub == 0) {
    double bv1 = acc[0];
#pragma unroll
    for (int e = 1; e < NEXP; ++e)
      if (acc[e] > bv1) { bv1 = acc[e]; i1 = e; }
    double bv2 = -1e300;
#pragma unroll
    for (int e = 0; e < NEXP; ++e)
      if (e != i1 && acc[e] > bv2) { bv2 = acc[e]; i2 = e; }
    float dd = expf((float)(bv2 - bv1));
    w1 = 1.0f / (1.0f + dd);
    w2 = dd * w1;
    o1 = atomicAdd(&lcnt[i1], 1);
    o2 = atomicAdd(&lcnt[i2], 1);
  }
  __syncthreads();
  if (tid < NEXP) lbase[tid] = atomicAdd(&cnt[tid], lcnt[tid]);
  __syncthreads();
  if (sub == 0) {
    int s1 = lbase[i1] + o1, s2 = lbase[i2] + o2;
    btok[i1 * NTOK + s1] = token;           // slot 0
    bw[i1 * NTOK + s1] = w1;
    btok[i2 * NTOK + s2] = token | 16384;   // slot 1 (bit 14)
    bw[i2 * NTOK + s2] = w2;
  }
}

// ---------------------------------------------------------------------------
// Expert FFN, round 4: 128-token tile, 512 threads (8 waves), double-buffered
// weight staging via global_load_lds (prefetch next chunk with a full phase-A
// of cover before the barrier's vmcnt drain). x fragments in registers.
// Epilogue: plain bf16 stores of w*(acc+b2) into pout[slot][token][col];
// a separate combine kernel sums the two slots (no atomics).
// LDS: wb1 2x32K + wb2 2x32K + hs 16K + misc ~2.5K = ~146.5 KiB -> 1 block/CU.
__global__ __launch_bounds__(512, 2) void ffn_kernel(
    const __bf16* __restrict__ xbf, const __bf16* __restrict__ w1bf,
    const __bf16* __restrict__ w2bf, const float* __restrict__ b1g,
    const float* __restrict__ b2g, const int* __restrict__ cnt,
    const int* __restrict__ btok, const float* __restrict__ bw,
    __bf16* __restrict__ pout) {
  __shared__ __align__(16) __bf16 wb1[2][64 * 256];   // [n64][k256], slot = c ^ (n&31)
  __shared__ __align__(16) __bf16 wb2[2][256 * 64];   // [n256][k64], slot = c ^ (n&7)
  __shared__ __align__(16) __bf16 hs[128 * 64];       // [m128][k64], slot = c ^ (m&7)
  __shared__ int tok[128];
  __shared__ int srow[128];   // pout row = slot*NTOK + token
  __shared__ float wgt[128];
  __shared__ float b2s[DOUT];

  const int tid = threadIdx.x;
  const int e = blockIdx.y;
  const int ce = cnt[e];
  const int start = blockIdx.x * 128;
  if (start >= ce) return;

  if (tid < 128) {
    int idx = start + tid;
    bool v = idx < ce;
    int entry = v ? btok[e * NTOK + idx] : 0;
    int t = entry & 16383;
    tok[tid] = t;
    srow[tid] = (entry >> 14) * NTOK + t;
    wgt[tid] = v ? bw[e * NTOK + idx] : 0.0f;
  }
  if (tid < DOUT) b2s[tid] = b2g[e * DOUT + tid];
  __syncthreads();

  const int lane = tid & 63;
  const int wid = tid >> 6;      // 0..7
  const int l15 = lane & 15;
  const int quad = lane >> 4;
  const int tt = wid & 3;        // token quarter (32)
  const int th = wid >> 2;       // phase A: hid half / phase B: out half (oh)

  // x fragments in registers: tokens tt*32 + {l15, l15+16}, full K=256.
  bf16x8 xA[2][8];
  {
    const __bf16* r0 = xbf + (size_t)tok[tt * 32 + l15] * DIN + quad * 8;
    const __bf16* r1 = xbf + (size_t)tok[tt * 32 + 16 + l15] * DIN + quad * 8;
#pragma unroll
    for (int kc = 0; kc < 8; ++kc) {
      xA[0][kc] = *(const bf16x8*)(r0 + kc * 32);
      xA[1][kc] = *(const bf16x8*)(r1 + kc * 32);
    }
  }

  const __bf16* w1e = w1bf + (size_t)e * DHID * DIN;
  const __bf16* w2e = w2bf + (size_t)e * DOUT * DHID;
  const int r1n = lane >> 5, s1 = lane & 31;  // W1 staging: row-in-window, slot
  const int r2n = lane >> 3, s2 = lane & 7;   // W2 staging

  // stage chunk 0 into buffer 0 (4 wb1 windows + 4 wb2 windows per wave)
#pragma unroll
  for (int j = 0; j < 4; ++j) {
    int W = wid * 4 + j;                 // 1KB window
    int n = 2 * W + r1n;
    int c = s1 ^ (n & 31);
    GLD16(w1e + (size_t)n * DIN + c * 8, (char*)wb1 + W * 1024);
    int n2 = 8 * W + r2n;
    int c2 = s2 ^ (n2 & 7);
    GLD16(w2e + (size_t)n2 * DHID + c2 * 8, (char*)wb2 + W * 1024);
  }

  f32x4 acc[2][8];
#pragma unroll
  for (int mt = 0; mt < 2; ++mt)
#pragma unroll
    for (int ni = 0; ni < 8; ++ni) acc[mt][ni] = (f32x4){0.f, 0.f, 0.f, 0.f};

  int p = 0;
  for (int hc = 0; hc < 8; ++hc, p ^= 1) {
    __syncthreads();  // closes prev chunk's phase B (and prologue staging)

    // prefetch next chunk into buffer p^1 (covered by phase A below)
    if (hc < 7) {
#pragma unroll
      for (int j = 0; j < 4; ++j) {
        int W = wid * 4 + j;
        int n = 2 * W + r1n;
        int c = s1 ^ (n & 31);
        GLD16(w1e + (size_t)((hc + 1) * 64 + n) * DIN + c * 8,
              (char*)wb1 + (p ^ 1) * 32768 + W * 1024);
        int n2 = 8 * W + r2n;
        int c2 = s2 ^ (n2 & 7);
        GLD16(w2e + (size_t)n2 * DHID + (hc + 1) * 64 + c2 * 8,
              (char*)wb2 + (p ^ 1) * 32768 + W * 1024);
      }
    }

    // ---- phase A: S[hid 32][tok 32] per wave = W1c-half x x-quarter
    f32x4 S[2][2];
#pragma unroll
    for (int g = 0; g < 2; ++g)
#pragma unroll
      for (int mt = 0; mt < 2; ++mt) S[g][mt] = (f32x4){0.f, 0.f, 0.f, 0.f};
#pragma unroll
    for (int kc = 0; kc < 8; ++kc) {
      int c = kc * 4 + quad;
      int n0 = th * 32 + l15, n1 = n0 + 16;
      bf16x8 w0 = *(const bf16x8*)((const char*)wb1 + p * 32768 + n0 * 512 +
                                   ((c ^ (n0 & 31)) << 4));
      bf16x8 w1v = *(const bf16x8*)((const char*)wb1 + p * 32768 + n1 * 512 +
                                    ((c ^ (n1 & 31)) << 4));
      S[0][0] = MFMA16(w0, xA[0][kc], S[0][0]);
      S[0][1] = MFMA16(w0, xA[1][kc], S[0][1]);
      S[1][0] = MFMA16(w1v, xA[0][kc], S[1][0]);
      S[1][1] = MFMA16(w1v, xA[1][kc], S[1][1]);
    }
    // bias + relu -> hs (8B writes, swizzled)
#pragma unroll
    for (int g = 0; g < 2; ++g) {
      int kl = th * 32 + g * 16 + quad * 4;  // local hid, 4-aligned
      f32x4 bv = *(const f32x4*)(b1g + e * DHID + hc * 64 + kl);
      int cpart = kl >> 3;
      int boff = (kl & 7) << 1;
#pragma unroll
      for (int mt = 0; mt < 2; ++mt) {
        int m = tt * 32 + mt * 16 + l15;
        bf16x4 pk;
#pragma unroll
        for (int r = 0; r < 4; ++r)
          pk[r] = (__bf16)fmaxf(S[g][mt][r] + bv[r], 0.f);
        *(bf16x4*)((char*)hs + m * 128 + ((cpart ^ (m & 7)) << 4) + boff) = pk;
      }
    }
    __syncthreads();  // hs visible; drains prefetch (had phase-A cover)

    // ---- phase B: acc[tok 32][out 128] += h x W2c
#pragma unroll
    for (int kc = 0; kc < 2; ++kc) {
      int c = kc * 4 + quad;
      int m0 = tt * 32 + l15, m1 = m0 + 16;
      bf16x8 h0 = *(const bf16x8*)((const char*)hs + m0 * 128 + ((c ^ (m0 & 7)) << 4));
      bf16x8 h1 = *(const bf16x8*)((const char*)hs + m1 * 128 + ((c ^ (m1 & 7)) << 4));
#pragma unroll
      for (int ni = 0; ni < 8; ++ni) {
        int n = th * 128 + ni * 16 + l15;
        bf16x8 bb = *(const bf16x8*)((const char*)wb2 + p * 32768 + n * 128 +
                                     ((c ^ (n & 7)) << 4));
        acc[0][ni] = MFMA16(h0, bb, acc[0][ni]);
        acc[1][ni] = MFMA16(h1, bb, acc[1][ni]);
      }
    }
  }

  // ---- epilogue: pout[srow[m]][n] = bf16(w * (acc + b2)), plain stores
#pragma unroll
  for (int ni = 0; ni < 8; ++ni) {
    int n = th * 128 + ni * 16 + l15;
    float b2v = b2s[n];
#pragma unroll
    for (int mt = 0; mt < 2; ++mt) {
#pragma unroll
      for (int r = 0; r < 4; ++r) {
        int m = tt * 32 + mt * 16 + quad * 4 + r;
        if (start + m < ce) {
          float v = wgt[m] * (acc[mt][ni][r] + b2v);
          pout[(size_t)srow[m] * DOUT + n] = (__bf16)v;
        }
      }
    }
  }
}

// ---------------------------------------------------------------------------
// out[t][c] = pout[0][t][c] + pout[1][t][c]   (streaming, 8 elems/thread)
__global__ __launch_bounds__(256) void combine_kernel(const __bf16* __restrict__ pout,
                                                      float* __restrict__ out) {
  int f = blockIdx.x * 256 + threadIdx.x;  // [0, NTOK*DOUT/8)
  bf16x8 a = *(const bf16x8*)(pout + (size_t)f * 8);
  bf16x8 b = *(const bf16x8*)(pout + (size_t)NTOK * DOUT + (size_t)f * 8);
  float4 o0, o1;
  o0.x = (float)a[0] + (float)b[0];
  o0.y = (float)a[1] + (float)b[1];
  o0.z = (float)a[2] + (float)b[2];
  o0.w = (float)a[3] + (float)b[3];
  o1.x = (float)a[4] + (float)b[4];
  o1.y = (float)a[5] + (float)b[5];
  o1.z = (float)a[6] + (float)b[6];
  o1.w = (float)a[7] + (float)b[7];
  float4* dst = (float4*)(out + (size_t)f * 8);
  dst[0] = o0;
  dst[1] = o1;
}

// ---------------------------------------------------------------------------
extern "C" void kernel_launch(void* const* d_in, const int* in_sizes, int n_in,
                              void* d_out, int out_size, void* d_ws, size_t ws_size,
                              hipStream_t stream) {
  const float* x = (const float*)d_in[0];
  const float* Wg = (const float*)d_in[1];
  const float* W1 = (const float*)d_in[2];
  const float* b1 = (const float*)d_in[3];
  const float* W2 = (const float*)d_in[4];
  const float* b2 = (const float*)d_in[5];
  float* out = (float*)d_out;

  char* ws = (char*)d_ws;
  int* cnt = (int*)(ws + 0);                    //      32 B
  int* btok = (int*)(ws + 256);                 //  512 KiB
  float* bw = (float*)(ws + 524544);            //  512 KiB
  __bf16* xbf = (__bf16*)(ws + 1048832);        //    8 MiB
  __bf16* w1bf = (__bf16*)(ws + 9437440);       //    2 MiB
  __bf16* w2bf = (__bf16*)(ws + 11534592);      //    2 MiB
  __bf16* pout = (__bf16*)(ws + 13631744);      //   16 MiB (end ~29 MiB)

  hipMemsetAsync(cnt, 0, NEXP * sizeof(int), stream);

  wcvt_kernel<<<dim3(64, NEXP), dim3(256), 0, stream>>>(W1, w1bf, DIN, 9);   // ->[E][512][256]
  wcvt_kernel<<<dim3(64, NEXP), dim3(256), 0, stream>>>(W2, w2bf, DHID, 8);  // ->[E][256][512]
  gate_kernel<<<dim3(NTOK / 32), dim3(256), 0, stream>>>(x, Wg, cnt, btok, bw, xbf);
  ffn_kernel<<<dim3(96, NEXP), dim3(512), 0, stream>>>(xbf, w1bf, w2bf, b1, b2,
                                                       cnt, btok, bw, pout);
  combine_kernel<<<dim3(NTOK * DOUT / 8 / 256), dim3(256), 0, stream>>>(pout, out);
}

// Round 5
// 161.668 us; speedup vs baseline: 2.1322x; 1.0577x over previous
//
#include <hip/hip_runtime.h>
#include <hip/hip_bf16.h>

typedef __bf16 bf16x8 __attribute__((ext_vector_type(8)));
typedef __bf16 bf16x4 __attribute__((ext_vector_type(4)));
typedef float f32x4 __attribute__((ext_vector_type(4)));
typedef float f32x16 __attribute__((ext_vector_type(16)));

#define NTOK 16384
#define DIN  256
#define DHID 512
#define DOUT 256
#define NEXP 8

#define MFMA32(a, b, c) __builtin_amdgcn_mfma_f32_32x32x16_bf16(a, b, c, 0, 0, 0)
// async global->LDS, 16B/lane; LDS dest = wave-uniform base + lane*16 (HW rule)
#define GLD16(gp, lp)                                                       \
  __builtin_amdgcn_global_load_lds(                                         \
      (__attribute__((address_space(1))) void*)(gp),                        \
      (__attribute__((address_space(3))) void*)(lp), 16, 0, 0)

// ---------------------------------------------------------------------------
// Merged transpose+cvt: blockIdx.x<64 -> W1 [E][256][512]->[E][512][256] bf16;
// else W2 [E][512][256]->[E][256][512] bf16.
__global__ __launch_bounds__(256) void wcvt_kernel(const float* __restrict__ w1,
                                                   const float* __restrict__ w2,
                                                   __bf16* __restrict__ w1bf,
                                                   __bf16* __restrict__ w2bf) {
  int e = blockIdx.y;
  bool isW1 = blockIdx.x < 64;
  int flat = (isW1 ? blockIdx.x : blockIdx.x - 64) * 256 + threadIdx.x;
  const float* src = isW1 ? w1 : w2;
  __bf16* dst = isW1 ? w1bf : w2bf;
  int K = isW1 ? DIN : DHID;       // dst row length
  int nsh = isW1 ? 9 : 8;          // N = 1<<nsh (dst rows)
  int N = 1 << nsh;
  int kg = flat >> nsh;
  int n = flat & (N - 1);
  const float* s = src + ((size_t)e * K + (size_t)kg * 8) * N + n;
  bf16x8 t;
#pragma unroll
  for (int j = 0; j < 8; ++j) t[j] = (__bf16)s[(size_t)j * N];
  *(bf16x8*)(dst + (size_t)((e << nsh) + n) * K + kg * 8) = t;
}

// ---------------------------------------------------------------------------
// Gating (8 lanes/token, 32 tokens/block) + fused x->bf16 conversion.
// Bucket entry packs the pick slot (0 = top1, 1 = top2) in bit 14.
__global__ __launch_bounds__(256) void gate_kernel(const float* __restrict__ x,
                                                   const float* __restrict__ wg,
                                                   int* __restrict__ cnt,
                                                   int* __restrict__ btok,
                                                   float* __restrict__ bw,
                                                   __bf16* __restrict__ xbf) {
  __shared__ int lcnt[NEXP];
  __shared__ int lbase[NEXP];
  const int tid = threadIdx.x;
  if (tid < NEXP) lcnt[tid] = 0;

  const int sub = tid & 7;        // 32-dim slice
  const int tslot = tid >> 3;     // 0..31
  const int token = blockIdx.x * 32 + tslot;
  const f32x4* xr = (const f32x4*)(x + (size_t)token * DIN + sub * 32);
  const float* wr0 = wg + (size_t)sub * 32 * NEXP;

  bf16x8 xb[4];
  f32x4 p0 = {0.f, 0.f, 0.f, 0.f}, p1 = {0.f, 0.f, 0.f, 0.f};
#pragma unroll
  for (int j4 = 0; j4 < 8; ++j4) {
    f32x4 xv = xr[j4];
    const float* wr = wr0 + j4 * 32;
#pragma unroll
    for (int d = 0; d < 4; ++d) {
      float xs_ = xv[d];
      p0 += xs_ * *(const f32x4*)(wr + 8 * d);
      p1 += xs_ * *(const f32x4*)(wr + 8 * d + 4);
      xb[j4 >> 1][(j4 & 1) * 4 + d] = (__bf16)xs_;
    }
  }
  {
    bf16x8* xdst = (bf16x8*)(xbf + (size_t)token * DIN + sub * 32);
#pragma unroll
    for (int i = 0; i < 4; ++i) xdst[i] = xb[i];
  }

  double acc[NEXP];
#pragma unroll
  for (int d = 0; d < 4; ++d) {
    acc[d] = (double)p0[d];
    acc[4 + d] = (double)p1[d];
  }
#pragma unroll
  for (int off = 1; off < 8; off <<= 1)
#pragma unroll
    for (int e = 0; e < NEXP; ++e) acc[e] += __shfl_xor(acc[e], off, 64);

  __syncthreads();  // lcnt zeroing visible

  int i1 = 0, i2 = 0, o1 = 0, o2 = 0;
  float w1 = 0.f, w2 = 0.f;
  if (sub == 0) {
    double bv1 = acc[0];
#pragma unroll
    for (int e = 1; e < NEXP; ++e)
      if (acc[e] > bv1) { bv1 = acc[e]; i1 = e; }
    double bv2 = -1e300;
#pragma unroll
    for (int e = 0; e < NEXP; ++e)
      if (e != i1 && acc[e] > bv2) { bv2 = acc[e]; i2 = e; }
    float dd = expf((float)(bv2 - bv1));
    w1 = 1.0f / (1.0f + dd);
    w2 = dd * w1;
    o1 = atomicAdd(&lcnt[i1], 1);
    o2 = atomicAdd(&lcnt[i2], 1);
  }
  __syncthreads();
  if (tid < NEXP) lbase[tid] = atomicAdd(&cnt[tid], lcnt[tid]);
  __syncthreads();
  if (sub == 0) {
    int s1 = lbase[i1] + o1, s2 = lbase[i2] + o2;
    btok[i1 * NTOK + s1] = token;           // slot 0
    bw[i1 * NTOK + s1] = w1;
    btok[i2 * NTOK + s2] = token | 16384;   // slot 1 (bit 14)
    bw[i2 * NTOK + s2] = w2;
  }
}

// ---------------------------------------------------------------------------
// Expert FFN, round 5: 64-token tiles, 256 threads (4 waves), 32x32x16 MFMA
// (2x FLOP per LDS byte vs 16x16x32). Exact-size flat grid: each block
// prefix-scans cnt to find (expert, tile). x fragments in registers (W1 read
// exactly once per block); phase B 64out x 64tok wave tiles (4 reads -> 4
// MFMAs). Single-buffered staging; 75.5 KiB LDS -> 2 blocks/CU so the other
// block's waves cover barrier/staging drains.
__global__ __launch_bounds__(256, 2) void ffn_kernel(
    const __bf16* __restrict__ xbf, const __bf16* __restrict__ w1bf,
    const __bf16* __restrict__ w2bf, const float* __restrict__ b1g,
    const float* __restrict__ b2g, const int* __restrict__ cnt,
    const int* __restrict__ btok, const float* __restrict__ bw,
    __bf16* __restrict__ pout) {
  __shared__ __align__(16) __bf16 wb1[64 * 256];   // [hid64][k256] 512B rows, slot^(n&31)
  __shared__ __align__(16) __bf16 wb2[256 * 64];   // [out256][k64] 128B rows, slot^(n&7)
  __shared__ __align__(16) __bf16 hs[64 * 64];     // [tok64][hid64] 128B rows, slot^(m&7)
  __shared__ int tok[64];
  __shared__ int srow[64];
  __shared__ float wgt[64];
  __shared__ float b2s[DOUT];

  // locate (expert, tile) via prefix over cnt
  int b = blockIdx.x;
  int e = -1, start = 0;
  {
    int a0 = 0;
#pragma unroll
    for (int q = 0; q < NEXP; ++q) {
      int t = (cnt[q] + 63) >> 6;
      if (e < 0 && b < a0 + t) { e = q; start = (b - a0) * 64; }
      a0 += t;
    }
  }
  if (e < 0) return;
  const int ce = cnt[e];

  const int tid = threadIdx.x;
  if (tid < 64) {
    int idx = start + tid;
    bool v = idx < ce;
    int entry = v ? btok[e * NTOK + idx] : 0;
    int t = entry & 16383;
    tok[tid] = t;
    srow[tid] = (entry >> 14) * NTOK + t;
    wgt[tid] = v ? bw[e * NTOK + idx] : 0.0f;
  }
  b2s[tid] = b2g[e * DOUT + tid];
  __syncthreads();

  const int lane = tid & 63;
  const int wid = tid >> 6;      // 0..3
  const int hi = lane >> 5;      // k-half selector
  const int l31 = lane & 31;
  const int wh = wid >> 1;       // phase A: hid half
  const int wt = wid & 1;        // phase A: tok half
  const int wo = wid;            // phase B: out quarter

  // x as B-operand in registers: B[k][n=tok], lane n = wt*32+l31, k-half hi.
  bf16x8 xB[16];
  {
    const __bf16* xr = xbf + (size_t)tok[wt * 32 + l31] * DIN + hi * 8;
#pragma unroll
    for (int kw = 0; kw < 16; ++kw) xB[kw] = *(const bf16x8*)(xr + kw * 16);
  }

  const __bf16* w1e = w1bf + (size_t)e * DHID * DIN;
  const __bf16* w2e = w2bf + (size_t)e * DOUT * DHID;

  f32x16 acc[2][2];
#pragma unroll
  for (int ai = 0; ai < 2; ++ai)
#pragma unroll
    for (int bi = 0; bi < 2; ++bi)
#pragma unroll
      for (int r = 0; r < 16; ++r) acc[ai][bi][r] = 0.f;

  for (int hc = 0; hc < 8; ++hc) {
    __syncthreads();  // prev chunk's readers done with wb1/wb2/hs

    // stage W1c (32 KiB) + W2c (32 KiB); swizzle via global-address permute
#pragma unroll
    for (int j = 0; j < 8; ++j) {
      int W = wid * 8 + j;               // 1 KiB window
      int n1 = 2 * W + hi;               // wb1 row
      int s1 = l31 ^ (n1 & 31);
      GLD16(w1e + (size_t)(hc * 64 + n1) * DIN + s1 * 8, wb1 + W * 512);
      int n2 = 8 * W + (lane >> 3);      // wb2 row
      int s2 = (lane & 7) ^ (n2 & 7);
      GLD16(w2e + (size_t)n2 * DHID + hc * 64 + s2 * 8, wb2 + W * 512);
    }
    __syncthreads();  // staging visible (vmcnt drain; other block covers)

    // ---- phase A: S[hid32 x tok32] = W1c-half x x-half, K=256
    f32x16 S;
#pragma unroll
    for (int r = 0; r < 16; ++r) S[r] = 0.f;
#pragma unroll
    for (int kw = 0; kw < 16; ++kw) {
      int row = wh * 32 + l31;
      int s = (kw * 2 + hi) ^ (row & 31);
      bf16x8 a = *(const bf16x8*)((const char*)wb1 + row * 512 + s * 16);
      S = MFMA32(a, xB[kw], S);
    }
    // bias + relu -> hs (8B swizzled writes); lane owns tok col, hid rows
#pragma unroll
    for (int g = 0; g < 4; ++g) {
      int hl = wh * 32 + 8 * g + 4 * hi;   // local hid, 4-aligned
      f32x4 bv = *(const f32x4*)(b1g + e * DHID + hc * 64 + hl);
      bf16x4 pk;
#pragma unroll
      for (int r = 0; r < 4; ++r)
        pk[r] = (__bf16)fmaxf(S[4 * g + r] + bv[r], 0.f);
      int m = wt * 32 + l31;               // token row
      int slot = (hl >> 3) ^ (m & 7);
      *(bf16x4*)((char*)hs + m * 128 + slot * 16 + (hl & 7) * 2) = pk;
    }
    __syncthreads();  // hs visible

    // ---- phase B: acc[out64 x tok64] += W2c x h, K=64
#pragma unroll
    for (int kw = 0; kw < 4; ++kw) {
      bf16x8 wf[2], hf[2];
#pragma unroll
      for (int ai = 0; ai < 2; ++ai) {
        int row = wo * 64 + ai * 32 + l31;
        int s = (kw * 2 + hi) ^ (row & 7);
        wf[ai] = *(const bf16x8*)((const char*)wb2 + row * 128 + s * 16);
      }
#pragma unroll
      for (int bi = 0; bi < 2; ++bi) {
        int m = bi * 32 + l31;
        int s = (kw * 2 + hi) ^ (m & 7);
        hf[bi] = *(const bf16x8*)((const char*)hs + m * 128 + s * 16);
      }
      acc[0][0] = MFMA32(wf[0], hf[0], acc[0][0]);
      acc[0][1] = MFMA32(wf[0], hf[1], acc[0][1]);
      acc[1][0] = MFMA32(wf[1], hf[0], acc[1][0]);
      acc[1][1] = MFMA32(wf[1], hf[1], acc[1][1]);
    }
  }

  // ---- epilogue: pout[srow[t]][o] = bf16(w * (acc + b2)), plain stores
#pragma unroll
  for (int bi = 0; bi < 2; ++bi) {
    int tm = bi * 32 + l31;
    if (start + tm < ce) {
      float wv = wgt[tm];
      __bf16* prow = pout + (size_t)srow[tm] * DOUT;
#pragma unroll
      for (int ai = 0; ai < 2; ++ai) {
#pragma unroll
        for (int g = 0; g < 4; ++g) {
          int o0 = wo * 64 + ai * 32 + 8 * g + 4 * hi;
          f32x4 bv = *(const f32x4*)(&b2s[o0]);
          bf16x4 pk;
#pragma unroll
          for (int r = 0; r < 4; ++r)
            pk[r] = (__bf16)(wv * (acc[ai][bi][4 * g + r] + bv[r]));
          *(bf16x4*)(prow + o0) = pk;
        }
      }
    }
  }
}

// ---------------------------------------------------------------------------
// out[t][c] = pout[0][t][c] + pout[1][t][c]   (streaming, 8 elems/thread)
__global__ __launch_bounds__(256) void combine_kernel(const __bf16* __restrict__ pout,
                                                      float* __restrict__ out) {
  int f = blockIdx.x * 256 + threadIdx.x;  // [0, NTOK*DOUT/8)
  bf16x8 a = *(const bf16x8*)(pout + (size_t)f * 8);
  bf16x8 b = *(const bf16x8*)(pout + (size_t)NTOK * DOUT + (size_t)f * 8);
  float4 o0, o1;
  o0.x = (float)a[0] + (float)b[0];
  o0.y = (float)a[1] + (float)b[1];
  o0.z = (float)a[2] + (float)b[2];
  o0.w = (float)a[3] + (float)b[3];
  o1.x = (float)a[4] + (float)b[4];
  o1.y = (float)a[5] + (float)b[5];
  o1.z = (float)a[6] + (float)b[6];
  o1.w = (float)a[7] + (float)b[7];
  float4* dst = (float4*)(out + (size_t)f * 8);
  dst[0] = o0;
  dst[1] = o1;
}

// ---------------------------------------------------------------------------
extern "C" void kernel_launch(void* const* d_in, const int* in_sizes, int n_in,
                              void* d_out, int out_size, void* d_ws, size_t ws_size,
                              hipStream_t stream) {
  const float* x = (const float*)d_in[0];
  const float* Wg = (const float*)d_in[1];
  const float* W1 = (const float*)d_in[2];
  const float* b1 = (const float*)d_in[3];
  const float* W2 = (const float*)d_in[4];
  const float* b2 = (const float*)d_in[5];
  float* out = (float*)d_out;

  char* ws = (char*)d_ws;
  int* cnt = (int*)(ws + 0);                    //      32 B
  int* btok = (int*)(ws + 256);                 //  512 KiB
  float* bw = (float*)(ws + 524544);            //  512 KiB
  __bf16* xbf = (__bf16*)(ws + 1048832);        //    8 MiB
  __bf16* w1bf = (__bf16*)(ws + 9437440);       //    2 MiB
  __bf16* w2bf = (__bf16*)(ws + 11534592);      //    2 MiB
  __bf16* pout = (__bf16*)(ws + 13631744);      //   16 MiB (end ~29 MiB)

  hipMemsetAsync(cnt, 0, NEXP * sizeof(int), stream);

  wcvt_kernel<<<dim3(128, NEXP), dim3(256), 0, stream>>>(W1, W2, w1bf, w2bf);
  gate_kernel<<<dim3(NTOK / 32), dim3(256), 0, stream>>>(x, Wg, cnt, btok, bw, xbf);
  ffn_kernel<<<dim3(520), dim3(256), 0, stream>>>(xbf, w1bf, w2bf, b1, b2,
                                                  cnt, btok, bw, pout);
  combine_kernel<<<dim3(NTOK * DOUT / 8 / 256), dim3(256), 0, stream>>>(pout, out);
}